// Round 17
// baseline (39.399 us; speedup 1.0000x reference)
//
#include <hip/hip_runtime.h>

// Problem constants (fixed by the reference).
#define BB   32
#define TT   2048
#define FF   512
#define KK   1024
#define DD   512
#define NCMAX 512        // max active timesteps: g>=0.05 -> g*(1-g)^c >= 1e-12 needs c <= 481
#define LN_EPS 1e-5f
#define WCUT 1e-12f      // drop terms with EMA weight < 1e-12 (bounded err ~5e-11 << 5.8e-2 thr)

typedef __attribute__((ext_vector_type(8))) short bf16x8;
typedef __attribute__((ext_vector_type(4))) float f32x4;

// g = clip(sigmoid(w1*cos(t1)cos(p1) + w2*cos(t2)cos(p2) + b_g), 0.05, 0.75)
__device__ __forceinline__ float compute_g(const float* th1, const float* ph1,
                                           const float* th2, const float* ph2,
                                           const float* w1, const float* w2,
                                           const float* bg) {
    float z1 = cosf(*th1) * cosf(*ph1);
    float z2 = cosf(*th2) * cosf(*ph2);
    float s  = (*w1) * z1 + (*w2) * z2 + (*bg);
    float sg = 1.0f / (1.0f + expf(-s));
    return fminf(fmaxf(sg, 0.05f), 0.75f);
}

// fp32 -> bf16 bits, round-to-nearest-even
__device__ __forceinline__ ushort f2bf(float x) {
    unsigned u = __float_as_uint(x);
    u += 0x7FFFu + ((u >> 16) & 1u);
    return (ushort)(u >> 16);
}

// ---- MFMA weight merge v3 (UNCHANGED from verified R16): C = Ww.Pw ->
//      octet-interleaved bf16 Cbf2[(f>>3)][d][f&7]. Coalesced Ww loads,
//      double-buffered LDS (1 sync/chunk), 2-deep register prefetch.
// Block 0: wj table + n_active. Block 1: zero d_out (base_ln atomics into it).
__global__ __launch_bounds__(256) void weight_merge(
    const float* __restrict__ Pw, const float* __restrict__ Ww,
    ushort* __restrict__ Cbf, float* __restrict__ wj, int* __restrict__ nact,
    float* __restrict__ out,
    const float* th1, const float* ph1, const float* th2, const float* ph2,
    const float* w1p, const float* w2p, const float* bgp) {

    __shared__ __align__(16) ushort As[2][32 * 16 * 8];   // [buf][d-row][slot] 2x8 KB
    __shared__ __align__(16) ushort Bs[2][32 * 16 * 8];   // [buf][f-row][slot] 2x8 KB
    __shared__ int cnt4[4];

    const int tid = threadIdx.x;

    // ---- preludes ----
    if (blockIdx.x == 0) {
        const float g   = compute_g(th1, ph1, th2, ph2, w1p, w2p, bgp);
        const float omg = 1.0f - g;
        const float w0  = g * powf(omg, (float)tid);
        const float w1  = g * powf(omg, (float)(tid + 256));
        wj[tid]       = w0;
        wj[tid + 256] = w1;
        const unsigned long long m0 = __ballot(w0 >= WCUT);
        const unsigned long long m1 = __ballot(w1 >= WCUT);
        if ((tid & 63) == 0) cnt4[tid >> 6] = __popcll(m0) + __popcll(m1);
        __syncthreads();
        if (tid == 0) *nact = cnt4[0] + cnt4[1] + cnt4[2] + cnt4[3];
    } else if (blockIdx.x == 1) {
        // zero d_out (BB*DD floats = 64 KB) for this launch's atomic accumulation
        float4 z = make_float4(0.f, 0.f, 0.f, 0.f);
        #pragma unroll
        for (int i = 0; i < BB * DD / 4 / 256; ++i)
            *(float4*)(out + (size_t)(i * 256 + tid) * 4) = z;
    }

    const int d0 = (blockIdx.x >> 4) * 32;
    const int f0 = (blockIdx.x & 15) * 32;

    const int wave = tid >> 6;
    const int lane = tid & 63;
    const int wm2  = wave >> 1;        // wave's d-half (16)
    const int wn2  = wave & 1;         // wave's f-half (16)
    const int lg   = lane >> 4;        // k-octet sub-group 0..3
    const int ll   = lane & 15;        // free-index lane

    // Ww staging (coalesced): row rwq, k-quads kq8 + it*8
    const int rwq = tid >> 3;          // 0..31 d-row
    const int kq8 = tid & 7;           // 0..7 k-float4 base
    // Pw staging (coalesced): f-lane srow, k-octet so / so+8
    const int srow = tid & 31;
    const int so   = tid >> 5;         // 0..7

    const int arow = wm2 * 16 + ll;    // frag rows
    const int brow = wn2 * 16 + ll;

    f32x4 accA = {0.f, 0.f, 0.f, 0.f};   // ks 0,2
    f32x4 accB = {0.f, 0.f, 0.f, 0.f};   // ks 1,3

    float4 aw[2][4];                   // Ww prefetch, 2-deep
    float  pb0[2][8], pb1[2][8];       // Pw prefetch, 2-deep

#define WM_LOAD(S, kkv) do {                                                      \
        const float* wr = Ww + (size_t)(d0 + rwq) * KK + (kkv) + kq8 * 4;         \
        _Pragma("unroll")                                                         \
        for (int it = 0; it < 4; ++it)                                            \
            aw[S][it] = *(const float4*)(wr + it * 32);                           \
        const float* pr = Pw + (size_t)(kkv) * FF + f0 + srow;                    \
        _Pragma("unroll")                                                         \
        for (int j = 0; j < 8; ++j) {                                             \
            pb0[S][j] = pr[(size_t)(so * 8 + j) * FF];                            \
            pb1[S][j] = pr[(size_t)((so + 8) * 8 + j) * FF];                      \
        }                                                                         \
    } while (0)

#define WM_STORE(S) do {                                                          \
        _Pragma("unroll")                                                         \
        for (int it = 0; it < 4; ++it) {                                          \
            const int oct  = (kq8 >> 1) + it * 4;                                 \
            const int half = kq8 & 1;                                            \
            ushort4 u;                                                            \
            u.x = f2bf(aw[S][it].x); u.y = f2bf(aw[S][it].y);                     \
            u.z = f2bf(aw[S][it].z); u.w = f2bf(aw[S][it].w);                     \
            *(ushort4*)&As[S][(rwq * 16 + (oct ^ (rwq & 15))) * 8 + half * 4] = u;\
        }                                                                         \
        bf16x8 vb0, vb1;                                                          \
        _Pragma("unroll")                                                         \
        for (int e = 0; e < 8; ++e) {                                             \
            vb0[e] = (short)f2bf(pb0[S][e]);                                      \
            vb1[e] = (short)f2bf(pb1[S][e]);                                      \
        }                                                                         \
        const int sw = srow & 15;                                                 \
        *(bf16x8*)&Bs[S][(srow * 16 + (so ^ sw)) * 8]       = vb0;                \
        *(bf16x8*)&Bs[S][(srow * 16 + ((so + 8) ^ sw)) * 8] = vb1;                \
    } while (0)

    WM_LOAD(0, 0);
    WM_LOAD(1, 128);

    #pragma unroll
    for (int k = 0; k < 8; ++k) {
        const int s = k & 1;
        WM_STORE(s);
        if (k + 2 < 8) WM_LOAD(s, (k + 2) * 128);   // 2-deep prefetch
        __syncthreads();
        #pragma unroll
        for (int ks = 0; ks < 4; ++ks) {
            const int oct = ks * 4 + lg;
            const bf16x8 af = *(const bf16x8*)&As[s][(arow * 16 + (oct ^ (arow & 15))) * 8];
            const bf16x8 bf = *(const bf16x8*)&Bs[s][(brow * 16 + (oct ^ (brow & 15))) * 8];
            if (ks & 1) accB = __builtin_amdgcn_mfma_f32_16x16x32_bf16(af, bf, accB, 0, 0, 0);
            else        accA = __builtin_amdgcn_mfma_f32_16x16x32_bf16(af, bf, accA, 0, 0, 0);
        }
        // no second sync: next iter writes the other buffer (safe: any wave's
        // iter-k write is after sync k-1, which is after all iter-k-2 reads)
    }
#undef WM_LOAD
#undef WM_STORE

    // epilogue: octet-interleaved store Cbf2[(f>>3)][d][f&7]
    // (D-layout HW-verified: col=lane&15 -> f, row=(lane>>4)*4+reg -> d)
    {
        const f32x4 acc = accA + accB;
        const int fb = f0 + wn2 * 16 + ll;
        const int db = d0 + wm2 * 16 + lg * 4;
        ushort* cp = Cbf + ((size_t)(fb >> 3) * DD) * 8 + (fb & 7);
        #pragma unroll
        for (int j = 0; j < 4; ++j)
            cp[(size_t)(db + j) * 8] = f2bf(acc[j]);
    }
}

// ---- base_ln v2: base = x . C^T (bf16 MFMA) -> +bias -> LayerNorm -> EMA ->
//      atomicAdd into out. R17 change: B-frag DEEP PREFETCH. Cbf is c-invariant
//      and independent of the x staging, so groups 0+1 (32 b128, 128 VGPR) are
//      issued BEFORE the staging __syncthreads (they fly under the x HBM
//      latency); groups 2,3 are issued as groups 0,1 are consumed (2-deep,
//      static register buffers). MFMA order per accumulator unchanged (ks
//      ascending) -> output bit-identical to R16.
__global__ __launch_bounds__(512) void base_ln(
    const float* __restrict__ x, const ushort* __restrict__ Cbf,
    const float* __restrict__ Wb, const float* __restrict__ bvec,
    const float* __restrict__ lng, const float* __restrict__ lnb,
    const float* __restrict__ wj, const int* __restrict__ nact,
    float* __restrict__ out) {

    const int nv = *nact;
    const int cslot = blockIdx.x;
    if (cslot >= nv) return;
    const int rh = blockIdx.y;

    __shared__ __align__(16) ushort xls[16 * 64 * 8];   // 16 KB
    __shared__ float redw[8][4][4][2];                  // [wave][lg][reg][S,Q] 1 KB

    const int tid  = threadIdx.x;
    const int w    = tid >> 6;
    const int lane = tid & 63;
    const int ll   = lane & 15;
    const int lg   = lane >> 4;

    // per-thread d-params: d_j = w*64 + j*16 + ll
    float bias[4], gam[4], bet[4];
    #pragma unroll
    for (int j = 0; j < 4; ++j) {
        const int d = w * 64 + j * 16 + ll;
        bias[j] = Wb[d] + bvec[d];
        gam[j]  = lng[d];
        bet[j]  = lnb[d];
    }

    float hacc[4][4];   // [j][reg]
    #pragma unroll
    for (int j = 0; j < 4; ++j)
        #pragma unroll
        for (int r = 0; r < 4; ++r) hacc[j][r] = 0.f;

// load B-frag group g (4 ks x 4 j = 16 b128) into static buffer BUF
#define BLOADG(BUF, g) do {                                                   \
        _Pragma("unroll")                                                     \
        for (int k2 = 0; k2 < 4; ++k2) {                                      \
            const int oct = ((g) * 4 + k2) * 4 + lg;                          \
            const ushort* cp = Cbf + ((size_t)oct * DD + w * 64 + ll) * 8;    \
            BUF[k2 * 4 + 0] = *(const bf16x8*)(cp);                           \
            BUF[k2 * 4 + 1] = *(const bf16x8*)(cp + 16 * 8);                  \
            BUF[k2 * 4 + 2] = *(const bf16x8*)(cp + 32 * 8);                  \
            BUF[k2 * 4 + 3] = *(const bf16x8*)(cp + 48 * 8);                  \
        }                                                                     \
    } while (0)

// MFMA group g from BUF (ks ascending within group; per-acc chain order
// identical to R16's ks=0..15 loop -> bit-identical results)
#define MFMAG(BUF, g) do {                                                    \
        _Pragma("unroll")                                                     \
        for (int k2 = 0; k2 < 4; ++k2) {                                      \
            const int oct = ((g) * 4 + k2) * 4 + lg;                          \
            const bf16x8 af = *(const bf16x8*)&xls[(ll * 64 + (oct ^ (ll & 7))) * 8]; \
            acc0 = __builtin_amdgcn_mfma_f32_16x16x32_bf16(af, BUF[k2 * 4 + 0], acc0, 0, 0, 0); \
            acc1 = __builtin_amdgcn_mfma_f32_16x16x32_bf16(af, BUF[k2 * 4 + 1], acc1, 0, 0, 0); \
            acc2 = __builtin_amdgcn_mfma_f32_16x16x32_bf16(af, BUF[k2 * 4 + 2], acc2, 0, 0, 0); \
            acc3 = __builtin_amdgcn_mfma_f32_16x16x32_bf16(af, BUF[k2 * 4 + 3], acc3, 0, 0, 0); \
        }                                                                     \
    } while (0)

    for (int c = cslot; c < nv; c += 64) {
        const int t = TT - 1 - c;

        // stage 16 x rows -> bf16 LDS, octet-swizzled (o ^ (r&7)); coalesced loads
        #pragma unroll
        for (int i2 = 0; i2 < 2; ++i2) {
            const int i = tid + i2 * 512;
            const int r = i >> 6, o = i & 63;
            const float* src = x + ((size_t)(rh * 16 + r) * TT + t) * FF + o * 8;
            const float4 u0 = *(const float4*)src;
            const float4 u1 = *(const float4*)(src + 4);
            bf16x8 v;
            v[0] = (short)f2bf(u0.x); v[1] = (short)f2bf(u0.y);
            v[2] = (short)f2bf(u0.z); v[3] = (short)f2bf(u0.w);
            v[4] = (short)f2bf(u1.x); v[5] = (short)f2bf(u1.y);
            v[6] = (short)f2bf(u1.z); v[7] = (short)f2bf(u1.w);
            *(bf16x8*)&xls[(r * 64 + (o ^ (r & 7))) * 8] = v;
        }

        // issue B-frag groups 0,1 BEFORE the sync: overlap with x HBM latency
        bf16x8 bA[16], bB[16];
        BLOADG(bA, 0);
        BLOADG(bB, 1);

        __syncthreads();

        f32x4 acc0 = {0.f,0.f,0.f,0.f}, acc1 = {0.f,0.f,0.f,0.f};
        f32x4 acc2 = {0.f,0.f,0.f,0.f}, acc3 = {0.f,0.f,0.f,0.f};

        MFMAG(bA, 0);
        BLOADG(bA, 2);      // 2-deep: refill while group 1 computes
        MFMAG(bB, 1);
        BLOADG(bB, 3);
        MFMAG(bA, 2);
        MFMAG(bB, 3);

        // v[j][reg] = raw base + bias
        float v[4][4];
        #pragma unroll
        for (int r = 0; r < 4; ++r) {
            v[0][r] = acc0[r] + bias[0];
            v[1][r] = acc1[r] + bias[1];
            v[2][r] = acc2[r] + bias[2];
            v[3][r] = acc3[r] + bias[3];
        }

        // LN stats per row (row = lg*4+reg): j in-reg, ll via shuffle, w via LDS
        float S[4], Q[4];
        #pragma unroll
        for (int r = 0; r < 4; ++r) {
            S[r] = v[0][r] + v[1][r] + v[2][r] + v[3][r];
            Q[r] = v[0][r]*v[0][r] + v[1][r]*v[1][r] + v[2][r]*v[2][r] + v[3][r]*v[3][r];
        }
        #pragma unroll
        for (int off = 8; off >= 1; off >>= 1) {
            #pragma unroll
            for (int r = 0; r < 4; ++r) {
                S[r] += __shfl_xor(S[r], off);
                Q[r] += __shfl_xor(Q[r], off);
            }
        }
        if (ll == 0) {
            #pragma unroll
            for (int r = 0; r < 4; ++r) {
                redw[w][lg][r][0] = S[r];
                redw[w][lg][r][1] = Q[r];
            }
        }
        __syncthreads();

        const float wjc = wj[c];
        #pragma unroll
        for (int r = 0; r < 4; ++r) {
            float SS = 0.f, QQ = 0.f;
            #pragma unroll
            for (int q = 0; q < 8; ++q) {
                SS += redw[q][lg][r][0];
                QQ += redw[q][lg][r][1];
            }
            const float mu   = SS * (1.0f / DD);
            const float rstd = rsqrtf(QQ * (1.0f / DD) - mu * mu + LN_EPS);
            #pragma unroll
            for (int j = 0; j < 4; ++j)
                hacc[j][r] += wjc * ((v[j][r] - mu) * rstd * gam[j] + bet[j]);
        }
        __syncthreads();   // protect xls/redw for next c
    }
#undef BLOADG
#undef MFMAG

    // accumulate into out (out zeroed by wm block 1)
    #pragma unroll
    for (int r = 0; r < 4; ++r) {
        const int row = rh * 16 + lg * 4 + r;
        #pragma unroll
        for (int j = 0; j < 4; ++j)
            atomicAdd(out + (size_t)row * DD + w * 64 + j * 16 + ll, hacc[j][r]);
    }
}

extern "C" void kernel_launch(void* const* d_in, const int* in_sizes, int n_in,
                              void* d_out, int out_size, void* d_ws, size_t ws_size,
                              hipStream_t stream) {
    const float* x   = (const float*)d_in[0];
    const float* Pw  = (const float*)d_in[1];
    const float* Ww  = (const float*)d_in[2];
    const float* Wb  = (const float*)d_in[3];
    const float* bv  = (const float*)d_in[4];
    const float* lng = (const float*)d_in[5];
    const float* lnb = (const float*)d_in[6];
    // d_in[7] = alpha: unused — alpha*cal_scalar is d-constant; LayerNorm cancels it exactly.
    const float* th1 = (const float*)d_in[8];
    const float* ph1 = (const float*)d_in[9];
    const float* th2 = (const float*)d_in[10];
    const float* ph2 = (const float*)d_in[11];
    const float* w1  = (const float*)d_in[12];
    const float* w2  = (const float*)d_in[13];
    const float* bg  = (const float*)d_in[14];

    ushort* Cbf  = (ushort*)d_ws;                      // [64][512][8] bf16 = 512 KB
    float*  wj   = (float*)((char*)d_ws + (1 << 19));  // [512] weight table
    int*    nact = (int*)(wj + 512);                   // active-count

    weight_merge<<<256, 256, 0, stream>>>(Pw, Ww, Cbf, wj, nact, (float*)d_out,
                                          th1, ph1, th2, ph2, w1, w2, bg);

    dim3 bgrid(64, 2);
    base_ln<<<bgrid, 512, 0, stream>>>(x, Cbf, Wb, bv, lng, lnb, wj, nact,
                                       (float*)d_out);
}

// Round 18
// 27.501 us; speedup vs baseline: 1.4327x; 1.4327x over previous
//
#include <hip/hip_runtime.h>

// Problem constants (fixed by the reference).
#define BB   32
#define TT   2048
#define FF   512
#define KK   1024
#define DD   512
#define NCMAX 512        // max active timesteps: g>=0.05 -> g*(1-g)^c >= 1e-12 needs c <= 481
#define LN_EPS 1e-5f
#define WCUT 1e-12f      // drop terms with EMA weight < 1e-12 (bounded err ~5e-11 << 5.8e-2 thr)

typedef __attribute__((ext_vector_type(8))) short bf16x8;
typedef __attribute__((ext_vector_type(4))) float f32x4;

// g = clip(sigmoid(w1*cos(t1)cos(p1) + w2*cos(t2)cos(p2) + b_g), 0.05, 0.75)
__device__ __forceinline__ float compute_g(const float* th1, const float* ph1,
                                           const float* th2, const float* ph2,
                                           const float* w1, const float* w2,
                                           const float* bg) {
    float z1 = cosf(*th1) * cosf(*ph1);
    float z2 = cosf(*th2) * cosf(*ph2);
    float s  = (*w1) * z1 + (*w2) * z2 + (*bg);
    float sg = 1.0f / (1.0f + expf(-s));
    return fminf(fmaxf(sg, 0.05f), 0.75f);
}

// fp32 -> bf16 bits, round-to-nearest-even
__device__ __forceinline__ ushort f2bf(float x) {
    unsigned u = __float_as_uint(x);
    u += 0x7FFFu + ((u >> 16) & 1u);
    return (ushort)(u >> 16);
}

// ---- MFMA weight merge v3 (UNCHANGED from verified R16): C = Ww.Pw ->
//      octet-interleaved bf16 Cbf2[(f>>3)][d][f&7]. Coalesced Ww loads,
//      double-buffered LDS (1 sync/chunk), 2-deep register prefetch.
// Block 0: wj table + n_active. Block 1: zero d_out (base_ln atomics into it).
__global__ __launch_bounds__(256) void weight_merge(
    const float* __restrict__ Pw, const float* __restrict__ Ww,
    ushort* __restrict__ Cbf, float* __restrict__ wj, int* __restrict__ nact,
    float* __restrict__ out,
    const float* th1, const float* ph1, const float* th2, const float* ph2,
    const float* w1p, const float* w2p, const float* bgp) {

    __shared__ __align__(16) ushort As[2][32 * 16 * 8];   // [buf][d-row][slot] 2x8 KB
    __shared__ __align__(16) ushort Bs[2][32 * 16 * 8];   // [buf][f-row][slot] 2x8 KB
    __shared__ int cnt4[4];

    const int tid = threadIdx.x;

    // ---- preludes ----
    if (blockIdx.x == 0) {
        const float g   = compute_g(th1, ph1, th2, ph2, w1p, w2p, bgp);
        const float omg = 1.0f - g;
        const float w0  = g * powf(omg, (float)tid);
        const float w1  = g * powf(omg, (float)(tid + 256));
        wj[tid]       = w0;
        wj[tid + 256] = w1;
        const unsigned long long m0 = __ballot(w0 >= WCUT);
        const unsigned long long m1 = __ballot(w1 >= WCUT);
        if ((tid & 63) == 0) cnt4[tid >> 6] = __popcll(m0) + __popcll(m1);
        __syncthreads();
        if (tid == 0) *nact = cnt4[0] + cnt4[1] + cnt4[2] + cnt4[3];
    } else if (blockIdx.x == 1) {
        // zero d_out (BB*DD floats = 64 KB) for this launch's atomic accumulation
        float4 z = make_float4(0.f, 0.f, 0.f, 0.f);
        #pragma unroll
        for (int i = 0; i < BB * DD / 4 / 256; ++i)
            *(float4*)(out + (size_t)(i * 256 + tid) * 4) = z;
    }

    const int d0 = (blockIdx.x >> 4) * 32;
    const int f0 = (blockIdx.x & 15) * 32;

    const int wave = tid >> 6;
    const int lane = tid & 63;
    const int wm2  = wave >> 1;        // wave's d-half (16)
    const int wn2  = wave & 1;         // wave's f-half (16)
    const int lg   = lane >> 4;        // k-octet sub-group 0..3
    const int ll   = lane & 15;        // free-index lane

    // Ww staging (coalesced): row rwq, k-quads kq8 + it*8
    const int rwq = tid >> 3;          // 0..31 d-row
    const int kq8 = tid & 7;           // 0..7 k-float4 base
    // Pw staging (coalesced): f-lane srow, k-octet so / so+8
    const int srow = tid & 31;
    const int so   = tid >> 5;         // 0..7

    const int arow = wm2 * 16 + ll;    // frag rows
    const int brow = wn2 * 16 + ll;

    f32x4 accA = {0.f, 0.f, 0.f, 0.f};   // ks 0,2
    f32x4 accB = {0.f, 0.f, 0.f, 0.f};   // ks 1,3

    float4 aw[2][4];                   // Ww prefetch, 2-deep
    float  pb0[2][8], pb1[2][8];       // Pw prefetch, 2-deep

#define WM_LOAD(S, kkv) do {                                                      \
        const float* wr = Ww + (size_t)(d0 + rwq) * KK + (kkv) + kq8 * 4;         \
        _Pragma("unroll")                                                         \
        for (int it = 0; it < 4; ++it)                                            \
            aw[S][it] = *(const float4*)(wr + it * 32);                           \
        const float* pr = Pw + (size_t)(kkv) * FF + f0 + srow;                    \
        _Pragma("unroll")                                                         \
        for (int j = 0; j < 8; ++j) {                                             \
            pb0[S][j] = pr[(size_t)(so * 8 + j) * FF];                            \
            pb1[S][j] = pr[(size_t)((so + 8) * 8 + j) * FF];                      \
        }                                                                         \
    } while (0)

#define WM_STORE(S) do {                                                          \
        _Pragma("unroll")                                                         \
        for (int it = 0; it < 4; ++it) {                                          \
            const int oct  = (kq8 >> 1) + it * 4;                                 \
            const int half = kq8 & 1;                                             \
            ushort4 u;                                                            \
            u.x = f2bf(aw[S][it].x); u.y = f2bf(aw[S][it].y);                     \
            u.z = f2bf(aw[S][it].z); u.w = f2bf(aw[S][it].w);                     \
            *(ushort4*)&As[S][(rwq * 16 + (oct ^ (rwq & 15))) * 8 + half * 4] = u;\
        }                                                                         \
        bf16x8 vb0, vb1;                                                          \
        _Pragma("unroll")                                                         \
        for (int e = 0; e < 8; ++e) {                                             \
            vb0[e] = (short)f2bf(pb0[S][e]);                                      \
            vb1[e] = (short)f2bf(pb1[S][e]);                                      \
        }                                                                         \
        const int sw = srow & 15;                                                 \
        *(bf16x8*)&Bs[S][(srow * 16 + (so ^ sw)) * 8]       = vb0;                \
        *(bf16x8*)&Bs[S][(srow * 16 + ((so + 8) ^ sw)) * 8] = vb1;                \
    } while (0)

    WM_LOAD(0, 0);
    WM_LOAD(1, 128);

    #pragma unroll
    for (int k = 0; k < 8; ++k) {
        const int s = k & 1;
        WM_STORE(s);
        if (k + 2 < 8) WM_LOAD(s, (k + 2) * 128);   // 2-deep prefetch
        __syncthreads();
        #pragma unroll
        for (int ks = 0; ks < 4; ++ks) {
            const int oct = ks * 4 + lg;
            const bf16x8 af = *(const bf16x8*)&As[s][(arow * 16 + (oct ^ (arow & 15))) * 8];
            const bf16x8 bf = *(const bf16x8*)&Bs[s][(brow * 16 + (oct ^ (brow & 15))) * 8];
            if (ks & 1) accB = __builtin_amdgcn_mfma_f32_16x16x32_bf16(af, bf, accB, 0, 0, 0);
            else        accA = __builtin_amdgcn_mfma_f32_16x16x32_bf16(af, bf, accA, 0, 0, 0);
        }
        // no second sync: next iter writes the other buffer (safe: any wave's
        // iter-k write is after sync k-1, which is after all iter-k-2 reads)
    }
#undef WM_LOAD
#undef WM_STORE

    // epilogue: octet-interleaved store Cbf2[(f>>3)][d][f&7]
    // (D-layout HW-verified: col=lane&15 -> f, row=(lane>>4)*4+reg -> d)
    {
        const f32x4 acc = accA + accB;
        const int fb = f0 + wn2 * 16 + ll;
        const int db = d0 + wm2 * 16 + lg * 4;
        ushort* cp = Cbf + ((size_t)(fb >> 3) * DD) * 8 + (fb & 7);
        #pragma unroll
        for (int j = 0; j < 4; ++j)
            cp[(size_t)(db + j) * 8] = f2bf(acc[j]);
    }
}

// ---- base_ln v3: R16 structure (verified 23.2us) + MINIMAL overlap: only B-frag
//      group 0 (16 b128 = 64 transient VGPR) is prefetched before the staging
//      sync; groups 1-3 load in-loop exactly as R16. (R17's 2-deep 128-VGPR
//      prefetch spilled and regressed 23->39us.) MFMA order per accumulator
//      unchanged -> output bit-identical.
__global__ __launch_bounds__(512) void base_ln(
    const float* __restrict__ x, const ushort* __restrict__ Cbf,
    const float* __restrict__ Wb, const float* __restrict__ bvec,
    const float* __restrict__ lng, const float* __restrict__ lnb,
    const float* __restrict__ wj, const int* __restrict__ nact,
    float* __restrict__ out) {

    const int nv = *nact;
    const int cslot = blockIdx.x;
    if (cslot >= nv) return;
    const int rh = blockIdx.y;

    __shared__ __align__(16) ushort xls[16 * 64 * 8];   // 16 KB
    __shared__ float redw[8][4][4][2];                  // [wave][lg][reg][S,Q] 1 KB

    const int tid  = threadIdx.x;
    const int w    = tid >> 6;
    const int lane = tid & 63;
    const int ll   = lane & 15;
    const int lg   = lane >> 4;

    // per-thread d-params: d_j = w*64 + j*16 + ll
    float bias[4], gam[4], bet[4];
    #pragma unroll
    for (int j = 0; j < 4; ++j) {
        const int d = w * 64 + j * 16 + ll;
        bias[j] = Wb[d] + bvec[d];
        gam[j]  = lng[d];
        bet[j]  = lnb[d];
    }

    float hacc[4][4];   // [j][reg]
    #pragma unroll
    for (int j = 0; j < 4; ++j)
        #pragma unroll
        for (int r = 0; r < 4; ++r) hacc[j][r] = 0.f;

    for (int c = cslot; c < nv; c += 64) {
        const int t = TT - 1 - c;

        // stage 16 x rows -> bf16 LDS, octet-swizzled (o ^ (r&7)); coalesced loads
        #pragma unroll
        for (int i2 = 0; i2 < 2; ++i2) {
            const int i = tid + i2 * 512;
            const int r = i >> 6, o = i & 63;
            const float* src = x + ((size_t)(rh * 16 + r) * TT + t) * FF + o * 8;
            const float4 u0 = *(const float4*)src;
            const float4 u1 = *(const float4*)(src + 4);
            bf16x8 v;
            v[0] = (short)f2bf(u0.x); v[1] = (short)f2bf(u0.y);
            v[2] = (short)f2bf(u0.z); v[3] = (short)f2bf(u0.w);
            v[4] = (short)f2bf(u1.x); v[5] = (short)f2bf(u1.y);
            v[6] = (short)f2bf(u1.z); v[7] = (short)f2bf(u1.w);
            *(bf16x8*)&xls[(r * 64 + (o ^ (r & 7))) * 8] = v;
        }

        // prefetch B-frag group 0 (ks 0..3) before the sync: overlaps x HBM latency
        bf16x8 b0[16];
        #pragma unroll
        for (int k2 = 0; k2 < 4; ++k2) {
            const int oct = k2 * 4 + lg;
            const ushort* cp = Cbf + ((size_t)oct * DD + w * 64 + ll) * 8;
            b0[k2 * 4 + 0] = *(const bf16x8*)(cp);
            b0[k2 * 4 + 1] = *(const bf16x8*)(cp + 16 * 8);
            b0[k2 * 4 + 2] = *(const bf16x8*)(cp + 32 * 8);
            b0[k2 * 4 + 3] = *(const bf16x8*)(cp + 48 * 8);
        }

        __syncthreads();

        f32x4 acc0 = {0.f,0.f,0.f,0.f}, acc1 = {0.f,0.f,0.f,0.f};
        f32x4 acc2 = {0.f,0.f,0.f,0.f}, acc3 = {0.f,0.f,0.f,0.f};

        // group 0 from the prefetch buffer (same ks order as R16)
        #pragma unroll
        for (int k2 = 0; k2 < 4; ++k2) {
            const int oct = k2 * 4 + lg;
            const bf16x8 af = *(const bf16x8*)&xls[(ll * 64 + (oct ^ (ll & 7))) * 8];
            acc0 = __builtin_amdgcn_mfma_f32_16x16x32_bf16(af, b0[k2 * 4 + 0], acc0, 0, 0, 0);
            acc1 = __builtin_amdgcn_mfma_f32_16x16x32_bf16(af, b0[k2 * 4 + 1], acc1, 0, 0, 0);
            acc2 = __builtin_amdgcn_mfma_f32_16x16x32_bf16(af, b0[k2 * 4 + 2], acc2, 0, 0, 0);
            acc3 = __builtin_amdgcn_mfma_f32_16x16x32_bf16(af, b0[k2 * 4 + 3], acc3, 0, 0, 0);
        }

        // groups 1-3 exactly as R16 (in-loop loads, compiler-scheduled)
        #pragma unroll 4
        for (int ks = 4; ks < 16; ++ks) {
            const int oct = ks * 4 + lg;
            const bf16x8 af = *(const bf16x8*)&xls[(ll * 64 + (oct ^ (ll & 7))) * 8];
            const ushort* cp = Cbf + ((size_t)oct * DD + w * 64 + ll) * 8;
            const bf16x8 bf0 = *(const bf16x8*)(cp);
            const bf16x8 bf1 = *(const bf16x8*)(cp + 16 * 8);
            const bf16x8 bf2 = *(const bf16x8*)(cp + 32 * 8);
            const bf16x8 bf3 = *(const bf16x8*)(cp + 48 * 8);
            acc0 = __builtin_amdgcn_mfma_f32_16x16x32_bf16(af, bf0, acc0, 0, 0, 0);
            acc1 = __builtin_amdgcn_mfma_f32_16x16x32_bf16(af, bf1, acc1, 0, 0, 0);
            acc2 = __builtin_amdgcn_mfma_f32_16x16x32_bf16(af, bf2, acc2, 0, 0, 0);
            acc3 = __builtin_amdgcn_mfma_f32_16x16x32_bf16(af, bf3, acc3, 0, 0, 0);
        }

        // v[j][reg] = raw base + bias
        float v[4][4];
        #pragma unroll
        for (int r = 0; r < 4; ++r) {
            v[0][r] = acc0[r] + bias[0];
            v[1][r] = acc1[r] + bias[1];
            v[2][r] = acc2[r] + bias[2];
            v[3][r] = acc3[r] + bias[3];
        }

        // LN stats per row (row = lg*4+reg): j in-reg, ll via shuffle, w via LDS
        float S[4], Q[4];
        #pragma unroll
        for (int r = 0; r < 4; ++r) {
            S[r] = v[0][r] + v[1][r] + v[2][r] + v[3][r];
            Q[r] = v[0][r]*v[0][r] + v[1][r]*v[1][r] + v[2][r]*v[2][r] + v[3][r]*v[3][r];
        }
        #pragma unroll
        for (int off = 8; off >= 1; off >>= 1) {
            #pragma unroll
            for (int r = 0; r < 4; ++r) {
                S[r] += __shfl_xor(S[r], off);
                Q[r] += __shfl_xor(Q[r], off);
            }
        }
        if (ll == 0) {
            #pragma unroll
            for (int r = 0; r < 4; ++r) {
                redw[w][lg][r][0] = S[r];
                redw[w][lg][r][1] = Q[r];
            }
        }
        __syncthreads();

        const float wjc = wj[c];
        #pragma unroll
        for (int r = 0; r < 4; ++r) {
            float SS = 0.f, QQ = 0.f;
            #pragma unroll
            for (int q = 0; q < 8; ++q) {
                SS += redw[q][lg][r][0];
                QQ += redw[q][lg][r][1];
            }
            const float mu   = SS * (1.0f / DD);
            const float rstd = rsqrtf(QQ * (1.0f / DD) - mu * mu + LN_EPS);
            #pragma unroll
            for (int j = 0; j < 4; ++j)
                hacc[j][r] += wjc * ((v[j][r] - mu) * rstd * gam[j] + bet[j]);
        }
        __syncthreads();   // protect xls/redw for next c
    }

    // accumulate into out (out zeroed by wm block 1)
    #pragma unroll
    for (int r = 0; r < 4; ++r) {
        const int row = rh * 16 + lg * 4 + r;
        #pragma unroll
        for (int j = 0; j < 4; ++j)
            atomicAdd(out + (size_t)row * DD + w * 64 + j * 16 + ll, hacc[j][r]);
    }
}

extern "C" void kernel_launch(void* const* d_in, const int* in_sizes, int n_in,
                              void* d_out, int out_size, void* d_ws, size_t ws_size,
                              hipStream_t stream) {
    const float* x   = (const float*)d_in[0];
    const float* Pw  = (const float*)d_in[1];
    const float* Ww  = (const float*)d_in[2];
    const float* Wb  = (const float*)d_in[3];
    const float* bv  = (const float*)d_in[4];
    const float* lng = (const float*)d_in[5];
    const float* lnb = (const float*)d_in[6];
    // d_in[7] = alpha: unused — alpha*cal_scalar is d-constant; LayerNorm cancels it exactly.
    const float* th1 = (const float*)d_in[8];
    const float* ph1 = (const float*)d_in[9];
    const float* th2 = (const float*)d_in[10];
    const float* ph2 = (const float*)d_in[11];
    const float* w1  = (const float*)d_in[12];
    const float* w2  = (const float*)d_in[13];
    const float* bg  = (const float*)d_in[14];

    ushort* Cbf  = (ushort*)d_ws;                      // [64][512][8] bf16 = 512 KB
    float*  wj   = (float*)((char*)d_ws + (1 << 19));  // [512] weight table
    int*    nact = (int*)(wj + 512);                   // active-count

    weight_merge<<<256, 256, 0, stream>>>(Pw, Ww, Cbf, wj, nact, (float*)d_out,
                                          th1, ph1, th2, ph2, w1, w2, bg);

    dim3 bgrid(64, 2);
    base_ln<<<bgrid, 512, 0, stream>>>(x, Cbf, Wb, bv, lng, lnb, wj, nact,
                                       (float*)d_out);
}

// Round 19
// 22.277 us; speedup vs baseline: 1.7686x; 1.2345x over previous
//
#include <hip/hip_runtime.h>

// Problem constants (fixed by the reference).
#define BB   32
#define TT   2048
#define FF   512
#define KK   1024
#define DD   512
#define NCMAX 512        // max active timesteps: g>=0.05 -> g*(1-g)^c >= 1e-12 needs c <= 481
#define LN_EPS 1e-5f
#define WCUT 1e-12f      // drop terms with EMA weight < 1e-12 (bounded err ~5e-11 << 5.8e-2 thr)

typedef __attribute__((ext_vector_type(8))) short bf16x8;
typedef __attribute__((ext_vector_type(4))) float f32x4;

// g = clip(sigmoid(w1*cos(t1)cos(p1) + w2*cos(t2)cos(p2) + b_g), 0.05, 0.75)
__device__ __forceinline__ float compute_g(const float* th1, const float* ph1,
                                           const float* th2, const float* ph2,
                                           const float* w1, const float* w2,
                                           const float* bg) {
    float z1 = cosf(*th1) * cosf(*ph1);
    float z2 = cosf(*th2) * cosf(*ph2);
    float s  = (*w1) * z1 + (*w2) * z2 + (*bg);
    float sg = 1.0f / (1.0f + expf(-s));
    return fminf(fmaxf(sg, 0.05f), 0.75f);
}

// fp32 -> bf16 bits, round-to-nearest-even
__device__ __forceinline__ ushort f2bf(float x) {
    unsigned u = __float_as_uint(x);
    u += 0x7FFFu + ((u >> 16) & 1u);
    return (ushort)(u >> 16);
}

// ---- MFMA weight merge v3 (UNCHANGED from verified R16): C = Ww.Pw ->
//      octet-interleaved bf16 Cbf2[(f>>3)][d][f&7]. Coalesced Ww loads,
//      double-buffered LDS (1 sync/chunk), 2-deep register prefetch.
// Block 0: wj table + n_active. Block 1: zero d_out (base_ln atomics into it).
__global__ __launch_bounds__(256) void weight_merge(
    const float* __restrict__ Pw, const float* __restrict__ Ww,
    ushort* __restrict__ Cbf, float* __restrict__ wj, int* __restrict__ nact,
    float* __restrict__ out,
    const float* th1, const float* ph1, const float* th2, const float* ph2,
    const float* w1p, const float* w2p, const float* bgp) {

    __shared__ __align__(16) ushort As[2][32 * 16 * 8];   // [buf][d-row][slot] 2x8 KB
    __shared__ __align__(16) ushort Bs[2][32 * 16 * 8];   // [buf][f-row][slot] 2x8 KB
    __shared__ int cnt4[4];

    const int tid = threadIdx.x;

    // ---- preludes ----
    if (blockIdx.x == 0) {
        const float g   = compute_g(th1, ph1, th2, ph2, w1p, w2p, bgp);
        const float omg = 1.0f - g;
        const float w0  = g * powf(omg, (float)tid);
        const float w1  = g * powf(omg, (float)(tid + 256));
        wj[tid]       = w0;
        wj[tid + 256] = w1;
        const unsigned long long m0 = __ballot(w0 >= WCUT);
        const unsigned long long m1 = __ballot(w1 >= WCUT);
        if ((tid & 63) == 0) cnt4[tid >> 6] = __popcll(m0) + __popcll(m1);
        __syncthreads();
        if (tid == 0) *nact = cnt4[0] + cnt4[1] + cnt4[2] + cnt4[3];
    } else if (blockIdx.x == 1) {
        // zero d_out (BB*DD floats = 64 KB) for this launch's atomic accumulation
        float4 z = make_float4(0.f, 0.f, 0.f, 0.f);
        #pragma unroll
        for (int i = 0; i < BB * DD / 4 / 256; ++i)
            *(float4*)(out + (size_t)(i * 256 + tid) * 4) = z;
    }

    const int d0 = (blockIdx.x >> 4) * 32;
    const int f0 = (blockIdx.x & 15) * 32;

    const int wave = tid >> 6;
    const int lane = tid & 63;
    const int wm2  = wave >> 1;        // wave's d-half (16)
    const int wn2  = wave & 1;         // wave's f-half (16)
    const int lg   = lane >> 4;        // k-octet sub-group 0..3
    const int ll   = lane & 15;        // free-index lane

    // Ww staging (coalesced): row rwq, k-quads kq8 + it*8
    const int rwq = tid >> 3;          // 0..31 d-row
    const int kq8 = tid & 7;           // 0..7 k-float4 base
    // Pw staging (coalesced): f-lane srow, k-octet so / so+8
    const int srow = tid & 31;
    const int so   = tid >> 5;         // 0..7

    const int arow = wm2 * 16 + ll;    // frag rows
    const int brow = wn2 * 16 + ll;

    f32x4 accA = {0.f, 0.f, 0.f, 0.f};   // ks 0,2
    f32x4 accB = {0.f, 0.f, 0.f, 0.f};   // ks 1,3

    float4 aw[2][4];                   // Ww prefetch, 2-deep
    float  pb0[2][8], pb1[2][8];       // Pw prefetch, 2-deep

#define WM_LOAD(S, kkv) do {                                                      \
        const float* wr = Ww + (size_t)(d0 + rwq) * KK + (kkv) + kq8 * 4;         \
        _Pragma("unroll")                                                         \
        for (int it = 0; it < 4; ++it)                                            \
            aw[S][it] = *(const float4*)(wr + it * 32);                           \
        const float* pr = Pw + (size_t)(kkv) * FF + f0 + srow;                    \
        _Pragma("unroll")                                                         \
        for (int j = 0; j < 8; ++j) {                                             \
            pb0[S][j] = pr[(size_t)(so * 8 + j) * FF];                            \
            pb1[S][j] = pr[(size_t)((so + 8) * 8 + j) * FF];                      \
        }                                                                         \
    } while (0)

#define WM_STORE(S) do {                                                          \
        _Pragma("unroll")                                                         \
        for (int it = 0; it < 4; ++it) {                                          \
            const int oct  = (kq8 >> 1) + it * 4;                                 \
            const int half = kq8 & 1;                                             \
            ushort4 u;                                                            \
            u.x = f2bf(aw[S][it].x); u.y = f2bf(aw[S][it].y);                     \
            u.z = f2bf(aw[S][it].z); u.w = f2bf(aw[S][it].w);                     \
            *(ushort4*)&As[S][(rwq * 16 + (oct ^ (rwq & 15))) * 8 + half * 4] = u;\
        }                                                                         \
        bf16x8 vb0, vb1;                                                          \
        _Pragma("unroll")                                                         \
        for (int e = 0; e < 8; ++e) {                                             \
            vb0[e] = (short)f2bf(pb0[S][e]);                                      \
            vb1[e] = (short)f2bf(pb1[S][e]);                                      \
        }                                                                         \
        const int sw = srow & 15;                                                 \
        *(bf16x8*)&Bs[S][(srow * 16 + (so ^ sw)) * 8]       = vb0;                \
        *(bf16x8*)&Bs[S][(srow * 16 + ((so + 8) ^ sw)) * 8] = vb1;                \
    } while (0)

    WM_LOAD(0, 0);
    WM_LOAD(1, 128);

    #pragma unroll
    for (int k = 0; k < 8; ++k) {
        const int s = k & 1;
        WM_STORE(s);
        if (k + 2 < 8) WM_LOAD(s, (k + 2) * 128);   // 2-deep prefetch
        __syncthreads();
        #pragma unroll
        for (int ks = 0; ks < 4; ++ks) {
            const int oct = ks * 4 + lg;
            const bf16x8 af = *(const bf16x8*)&As[s][(arow * 16 + (oct ^ (arow & 15))) * 8];
            const bf16x8 bf = *(const bf16x8*)&Bs[s][(brow * 16 + (oct ^ (brow & 15))) * 8];
            if (ks & 1) accB = __builtin_amdgcn_mfma_f32_16x16x32_bf16(af, bf, accB, 0, 0, 0);
            else        accA = __builtin_amdgcn_mfma_f32_16x16x32_bf16(af, bf, accA, 0, 0, 0);
        }
        // no second sync: next iter writes the other buffer (safe: any wave's
        // iter-k write is after sync k-1, which is after all iter-k-2 reads)
    }
#undef WM_LOAD
#undef WM_STORE

    // epilogue: octet-interleaved store Cbf2[(f>>3)][d][f&7]
    // (D-layout HW-verified: col=lane&15 -> f, row=(lane>>4)*4+reg -> d)
    {
        const f32x4 acc = accA + accB;
        const int fb = f0 + wn2 * 16 + ll;
        const int db = d0 + wm2 * 16 + lg * 4;
        ushort* cp = Cbf + ((size_t)(fb >> 3) * DD) * 8 + (fb & 7);
        #pragma unroll
        for (int j = 0; j < 4; ++j)
            cp[(size_t)(db + j) * 8] = f2bf(acc[j]);
    }
}

// ---- base_ln (R16 structure restored verbatim — the 23.2us optimum; R17/R18's
//      manual prefetch buffers both regressed). Only change vs R16: ks-loop
//      unroll 4 -> 8 (wider compiler scheduling window; compiler remains free
//      to not hoist loads). MFMA chain order unchanged -> bit-identical output.
__global__ __launch_bounds__(512) void base_ln(
    const float* __restrict__ x, const ushort* __restrict__ Cbf,
    const float* __restrict__ Wb, const float* __restrict__ bvec,
    const float* __restrict__ lng, const float* __restrict__ lnb,
    const float* __restrict__ wj, const int* __restrict__ nact,
    float* __restrict__ out) {

    const int nv = *nact;
    const int cslot = blockIdx.x;
    if (cslot >= nv) return;
    const int rh = blockIdx.y;

    __shared__ __align__(16) ushort xls[16 * 64 * 8];   // 16 KB
    __shared__ float redw[8][4][4][2];                  // [wave][lg][reg][S,Q] 1 KB

    const int tid  = threadIdx.x;
    const int w    = tid >> 6;
    const int lane = tid & 63;
    const int ll   = lane & 15;
    const int lg   = lane >> 4;

    // per-thread d-params: d_j = w*64 + j*16 + ll
    float bias[4], gam[4], bet[4];
    #pragma unroll
    for (int j = 0; j < 4; ++j) {
        const int d = w * 64 + j * 16 + ll;
        bias[j] = Wb[d] + bvec[d];
        gam[j]  = lng[d];
        bet[j]  = lnb[d];
    }

    float hacc[4][4];   // [j][reg]
    #pragma unroll
    for (int j = 0; j < 4; ++j)
        #pragma unroll
        for (int r = 0; r < 4; ++r) hacc[j][r] = 0.f;

    for (int c = cslot; c < nv; c += 64) {
        const int t = TT - 1 - c;

        // stage 16 x rows -> bf16 LDS, octet-swizzled (o ^ (r&7)); coalesced loads
        #pragma unroll
        for (int i2 = 0; i2 < 2; ++i2) {
            const int i = tid + i2 * 512;
            const int r = i >> 6, o = i & 63;
            const float* src = x + ((size_t)(rh * 16 + r) * TT + t) * FF + o * 8;
            const float4 u0 = *(const float4*)src;
            const float4 u1 = *(const float4*)(src + 4);
            bf16x8 v;
            v[0] = (short)f2bf(u0.x); v[1] = (short)f2bf(u0.y);
            v[2] = (short)f2bf(u0.z); v[3] = (short)f2bf(u0.w);
            v[4] = (short)f2bf(u1.x); v[5] = (short)f2bf(u1.y);
            v[6] = (short)f2bf(u1.z); v[7] = (short)f2bf(u1.w);
            *(bf16x8*)&xls[(r * 64 + (o ^ (r & 7))) * 8] = v;
        }
        __syncthreads();

        f32x4 acc0 = {0.f,0.f,0.f,0.f}, acc1 = {0.f,0.f,0.f,0.f};
        f32x4 acc2 = {0.f,0.f,0.f,0.f}, acc3 = {0.f,0.f,0.f,0.f};

        #pragma unroll 8
        for (int ks = 0; ks < 16; ++ks) {
            const int oct = ks * 4 + lg;
            const bf16x8 af = *(const bf16x8*)&xls[(ll * 64 + (oct ^ (ll & 7))) * 8];
            // octet-interleaved: 16 lanes -> 256 B contiguous per j
            const ushort* cp = Cbf + ((size_t)oct * DD + w * 64 + ll) * 8;
            const bf16x8 bf0 = *(const bf16x8*)(cp);
            const bf16x8 bf1 = *(const bf16x8*)(cp + 16 * 8);
            const bf16x8 bf2 = *(const bf16x8*)(cp + 32 * 8);
            const bf16x8 bf3 = *(const bf16x8*)(cp + 48 * 8);
            acc0 = __builtin_amdgcn_mfma_f32_16x16x32_bf16(af, bf0, acc0, 0, 0, 0);
            acc1 = __builtin_amdgcn_mfma_f32_16x16x32_bf16(af, bf1, acc1, 0, 0, 0);
            acc2 = __builtin_amdgcn_mfma_f32_16x16x32_bf16(af, bf2, acc2, 0, 0, 0);
            acc3 = __builtin_amdgcn_mfma_f32_16x16x32_bf16(af, bf3, acc3, 0, 0, 0);
        }

        // v[j][reg] = raw base + bias
        float v[4][4];
        #pragma unroll
        for (int r = 0; r < 4; ++r) {
            v[0][r] = acc0[r] + bias[0];
            v[1][r] = acc1[r] + bias[1];
            v[2][r] = acc2[r] + bias[2];
            v[3][r] = acc3[r] + bias[3];
        }

        // LN stats per row (row = lg*4+reg): j in-reg, ll via shuffle, w via LDS
        float S[4], Q[4];
        #pragma unroll
        for (int r = 0; r < 4; ++r) {
            S[r] = v[0][r] + v[1][r] + v[2][r] + v[3][r];
            Q[r] = v[0][r]*v[0][r] + v[1][r]*v[1][r] + v[2][r]*v[2][r] + v[3][r]*v[3][r];
        }
        #pragma unroll
        for (int off = 8; off >= 1; off >>= 1) {
            #pragma unroll
            for (int r = 0; r < 4; ++r) {
                S[r] += __shfl_xor(S[r], off);
                Q[r] += __shfl_xor(Q[r], off);
            }
        }
        if (ll == 0) {
            #pragma unroll
            for (int r = 0; r < 4; ++r) {
                redw[w][lg][r][0] = S[r];
                redw[w][lg][r][1] = Q[r];
            }
        }
        __syncthreads();

        const float wjc = wj[c];
        #pragma unroll
        for (int r = 0; r < 4; ++r) {
            float SS = 0.f, QQ = 0.f;
            #pragma unroll
            for (int q = 0; q < 8; ++q) {
                SS += redw[q][lg][r][0];
                QQ += redw[q][lg][r][1];
            }
            const float mu   = SS * (1.0f / DD);
            const float rstd = rsqrtf(QQ * (1.0f / DD) - mu * mu + LN_EPS);
            #pragma unroll
            for (int j = 0; j < 4; ++j)
                hacc[j][r] += wjc * ((v[j][r] - mu) * rstd * gam[j] + bet[j]);
        }
        __syncthreads();   // protect xls/redw for next c
    }

    // accumulate into out (out zeroed by wm block 1)
    #pragma unroll
    for (int r = 0; r < 4; ++r) {
        const int row = rh * 16 + lg * 4 + r;
        #pragma unroll
        for (int j = 0; j < 4; ++j)
            atomicAdd(out + (size_t)row * DD + w * 64 + j * 16 + ll, hacc[j][r]);
    }
}

extern "C" void kernel_launch(void* const* d_in, const int* in_sizes, int n_in,
                              void* d_out, int out_size, void* d_ws, size_t ws_size,
                              hipStream_t stream) {
    const float* x   = (const float*)d_in[0];
    const float* Pw  = (const float*)d_in[1];
    const float* Ww  = (const float*)d_in[2];
    const float* Wb  = (const float*)d_in[3];
    const float* bv  = (const float*)d_in[4];
    const float* lng = (const float*)d_in[5];
    const float* lnb = (const float*)d_in[6];
    // d_in[7] = alpha: unused — alpha*cal_scalar is d-constant; LayerNorm cancels it exactly.
    const float* th1 = (const float*)d_in[8];
    const float* ph1 = (const float*)d_in[9];
    const float* th2 = (const float*)d_in[10];
    const float* ph2 = (const float*)d_in[11];
    const float* w1  = (const float*)d_in[12];
    const float* w2  = (const float*)d_in[13];
    const float* bg  = (const float*)d_in[14];

    ushort* Cbf  = (ushort*)d_ws;                      // [64][512][8] bf16 = 512 KB
    float*  wj   = (float*)((char*)d_ws + (1 << 19));  // [512] weight table
    int*    nact = (int*)(wj + 512);                   // active-count

    weight_merge<<<256, 256, 0, stream>>>(Pw, Ww, Cbf, wj, nact, (float*)d_out,
                                          th1, ph1, th2, ph2, w1, w2, bg);

    dim3 bgrid(64, 2);
    base_ln<<<bgrid, 512, 0, stream>>>(x, Cbf, Wb, bv, lng, lnb, wj, nact,
                                       (float*)d_out);
}